// Round 1
// 134.906 us; speedup vs baseline: 1.0019x; 1.0019x over previous
//
#include <hip/hip_runtime.h>
#include <stdint.h>

#define U 128
#define V 128
#define IN_STRIDE 512
#define OUT_STRIDE 512
#define W_STRIDE (8 * U * V) /* 131072 floats per expert */
#define NB 32768
#define NE 4

// Workspace layout (bytes)
#define WS_WSHUF 0           // 524288 ushorts (1 MB) shuffled bf16 weights
#define WS_CNT   1048576     // 4 uint per-expert cursors/counts (16 B)
#define WS_SORT  1048640     // 4 * 32768 ints (512 KB): region e at e*NB

typedef __bf16 bf16x8 __attribute__((ext_vector_type(8)));
typedef float f32x16 __attribute__((ext_vector_type(16)));
typedef unsigned int u32x4 __attribute__((ext_vector_type(4)));
typedef unsigned int u32x2 __attribute__((ext_vector_type(2)));

static __device__ __forceinline__ unsigned short f2bf(float f) {
    unsigned int u = __builtin_bit_cast(unsigned int, f);
    u += 0x7FFFu + ((u >> 16) & 1u);   // round-to-nearest-even
    return (unsigned short)(u >> 16);
}

// ---------------------------------------------------------------------------
// prep: weights fp32 -> bf16 in MFMA B-fragment layout (unchanged layout).
//   flat short index = ((((e*8+s)*4+nt)*8+kt)*64+lane)*8 + j
//   element = W[e][s][k = kt*16+(lane>>5)*8+j][n = nt*32+(lane&31)], segs 4..7 x0.5
// Also zeroes the 4 expert cursors (stream order guarantees visibility).
// ---------------------------------------------------------------------------
__global__ void prep_kernel(const float* __restrict__ w, unsigned short* __restrict__ wshuf,
                            unsigned int* __restrict__ cnt) {
    if (blockIdx.x == 0 && threadIdx.x < NE) cnt[threadIdx.x] = 0u;
    int t = blockIdx.x * 256 + threadIdx.x;   // 0..65535
    int lane = t & 63;
    int kt = (t >> 6) & 7;
    int nt = (t >> 9) & 3;
    int s  = (t >> 11) & 7;
    int e  = (t >> 14) & 3;
    int kbase = kt * 16 + ((lane >> 5) << 3);
    int n = nt * 32 + (lane & 31);
    const float* src = w + (size_t)e * W_STRIDE + (size_t)s * (U * V) + n;
    float sc = (s >= 4) ? 0.5f : 1.0f;
    __attribute__((aligned(16))) unsigned short o[8];
#pragma unroll
    for (int j = 0; j < 8; j++) o[j] = f2bf(src[(size_t)(kbase + j) * V] * sc);
    *(u32x4*)(wshuf + (size_t)t * 8) = *(const u32x4*)o;
}

// ---------------------------------------------------------------------------
// scatter: bucket rows by expert (order within expert irrelevant).
// Two-level: LDS cursors per block, then ONE global atomicAdd per expert per
// block (512 global atomics total). After completion cnt[e] = count(e) and
// sorted[e*NB + 0..cnt[e]) holds the row ids of expert e.
// ---------------------------------------------------------------------------
__global__ void scatter_kernel(const int* __restrict__ wid, unsigned int* __restrict__ cnt,
                               int* __restrict__ sorted) {
    __shared__ unsigned int lcnt[NE];
    __shared__ unsigned int lbase[NE];
    int t = threadIdx.x;
    if (t < NE) lcnt[t] = 0u;
    __syncthreads();
    int i = blockIdx.x * 256 + t;
    int e = wid[i];
    unsigned int lpos = atomicAdd(&lcnt[e], 1u);
    __syncthreads();
    if (t < NE) lbase[t] = atomicAdd(&cnt[t], lcnt[t]);
    __syncthreads();
    sorted[e * NB + (int)(lbase[e] + lpos)] = i;
}

// ---------------------------------------------------------------------------
// gemm R5: expert-sorted. Block p handles sorted-order rows p*64..p*64+63
// (gathered through the per-expert lists; prefix computed from cnt[]).
// >=509 of 512 blocks are single-expert -> fast path: no A-masking, 1 pass
// over e (64 MFMAs/wave instead of 256, 256 KB B-reads/block instead of 1 MB).
// Boundary blocks (<=3) take the original 4-expert masked path.
// X staged once to LDS bf16 with XOR pack swizzle:
//   (r,c) at shorts offset r*512 + (((c>>3) ^ (r&7))<<3) + (c&7)
// 8 waves: wave w -> kout=w>>1 (out block), nhalf=w&1 (64-col half).
// K=256 per kout: x-block kout (seg kout) ++ x-block (kout+3)&3 (seg +4, x0.5
// pre-folded). Epilogue scatters to out[rowid[rl]] (row ids kept in LDS).
// LDS ~64 KB -> 2 blocks/CU; __launch_bounds__(512,4) keeps VGPR <= 128.
// ---------------------------------------------------------------------------
__global__ __launch_bounds__(512, 4) void gemm_kernel(
        const float* __restrict__ x, const unsigned short* __restrict__ wshuf,
        const unsigned int* __restrict__ cnt, const int* __restrict__ sorted,
        float* __restrict__ out) {
    const int rowbase = blockIdx.x * 64;
    __shared__ unsigned short lds[64 * 512];   // 64 KB
    __shared__ int rowid[64];

    const unsigned int p1 = cnt[0];
    const unsigned int p2 = p1 + cnt[1];
    const unsigned int p3 = p2 + cnt[2];

    const int t = threadIdx.x;

    // ---- stage X tile (sorted-order rows, gathered), fp32 -> bf16, swizzled ----
    {
        int r = t >> 3;            // 0..63
        int g = t & 7;
        unsigned int l = (unsigned int)(rowbase + r);
        int e = (l >= p1) + (l >= p2) + (l >= p3);
        unsigned int pe = (e == 0) ? 0u : (e == 1) ? p1 : (e == 2) ? p2 : p3;
        int row = sorted[e * NB + (int)(l - pe)];
        if (g == 0) rowid[r] = row;
        const float* xr = x + (size_t)row * IN_STRIDE;
        unsigned short* Lrow = lds + r * 512;
        int rs = r & 7;
#pragma unroll
        for (int i = 0; i < 16; i++) {
            int c = g * 4 + i * 32;
            float4 v = *(const float4*)(xr + c);
            __attribute__((aligned(8))) unsigned short h[4];
            h[0] = f2bf(v.x); h[1] = f2bf(v.y); h[2] = f2bf(v.z); h[3] = f2bf(v.w);
            int off = ((((c >> 3) ^ rs)) << 3) + (c & 7);
            *(u32x2*)(Lrow + off) = *(const u32x2*)h;
        }
    }

    const int w = t >> 6, lane = t & 63;
    const int kout = w >> 1, nhalf = w & 1;
    const int m0 = lane & 31;
    const int khalf3 = (lane >> 5);            // 0/1: k-offset/8 within k-tile
    const int rowswz = m0 & 7;

    // experts of this lane's two rows (from sorted-order position)
    const unsigned int l0 = (unsigned int)(rowbase + m0);
    const unsigned int l1 = l0 + 32u;
    const int e0 = (l0 >= p1) + (l0 >= p2) + (l0 >= p3);
    const int e1 = (l1 >= p1) + (l1 >= p2) + (l1 >= p3);
    const unsigned int lh = (unsigned int)rowbase, lt = (unsigned int)(rowbase + 63);
    const int ehead = (lh >= p1) + (lh >= p2) + (lh >= p3);
    const int etail = (lt >= p1) + (lt >= p2) + (lt >= p3);

    __syncthreads();   // single barrier

    f32x16 acc00 = {}, acc01 = {}, acc10 = {}, acc11 = {};

    const int xbs1 = (kout + 3) & 3;
    int xbs[2] = {kout, xbs1};
    int sgs[2] = {kout, xbs1 + 4};

    const unsigned short* Lr0 = lds + m0 * 512;
    const unsigned short* Lr1 = lds + (m0 + 32) * 512;

    if (ehead == etail) {
        // ---- fast path: whole block is one expert ----
        const int eu = ehead;
#pragma unroll
        for (int c = 0; c < 2; c++) {
            int colbase3 = xbs[c] * 16;   // (xb*128)>>3
            const unsigned short* wseg =
                wshuf + ((size_t)((eu * 8 + sgs[c]) * 4 + nhalf * 2) * 8) * 512 + (size_t)lane * 8;
#pragma unroll
            for (int kt = 0; kt < 8; kt++) {
                int kabs3 = colbase3 + kt * 2 + khalf3;
                int packoff = ((kabs3 ^ rowswz) << 3);
                bf16x8 a0 = __builtin_bit_cast(bf16x8, *(const u32x4*)(Lr0 + packoff));
                bf16x8 a1 = __builtin_bit_cast(bf16x8, *(const u32x4*)(Lr1 + packoff));
                bf16x8 b0 = __builtin_bit_cast(bf16x8, *(const u32x4*)(wseg + (size_t)kt * 512));
                bf16x8 b1 = __builtin_bit_cast(bf16x8, *(const u32x4*)(wseg + (size_t)(8 + kt) * 512));
                acc00 = __builtin_amdgcn_mfma_f32_32x32x16_bf16(a0, b0, acc00, 0, 0, 0);
                acc01 = __builtin_amdgcn_mfma_f32_32x32x16_bf16(a0, b1, acc01, 0, 0, 0);
                acc10 = __builtin_amdgcn_mfma_f32_32x32x16_bf16(a1, b0, acc10, 0, 0, 0);
                acc11 = __builtin_amdgcn_mfma_f32_32x32x16_bf16(a1, b1, acc11, 0, 0, 0);
            }
        }
    } else {
        // ---- boundary block (<=3 of 512): original 4-expert masked path ----
        unsigned int msk0[4], msk1[4];
#pragma unroll
        for (int e = 0; e < 4; e++) {
            msk0[e] = (e0 == e) ? 0xFFFFFFFFu : 0u;
            msk1[e] = (e1 == e) ? 0xFFFFFFFFu : 0u;
        }
#pragma unroll
        for (int c = 0; c < 2; c++) {
            int colbase3 = xbs[c] * 16;
#pragma unroll
            for (int kt = 0; kt < 8; kt++) {
                int kabs3 = colbase3 + kt * 2 + khalf3;
                int packoff = ((kabs3 ^ rowswz) << 3);
                u32x4 a0u = *(const u32x4*)(Lr0 + packoff);
                u32x4 a1u = *(const u32x4*)(Lr1 + packoff);
#pragma unroll
                for (int e = 0; e < 4; e++) {
                    const unsigned short* wseg =
                        wshuf + ((size_t)((e * 8 + sgs[c]) * 4 + nhalf * 2) * 8) * 512;
                    bf16x8 b0 = __builtin_bit_cast(bf16x8, *(const u32x4*)(wseg + (size_t)kt * 512 + lane * 8));
                    bf16x8 b1 = __builtin_bit_cast(bf16x8, *(const u32x4*)(wseg + (size_t)(8 + kt) * 512 + lane * 8));
                    u32x4 mm0 = {msk0[e], msk0[e], msk0[e], msk0[e]};
                    u32x4 mm1 = {msk1[e], msk1[e], msk1[e], msk1[e]};
                    bf16x8 a0m = __builtin_bit_cast(bf16x8, a0u & mm0);
                    bf16x8 a1m = __builtin_bit_cast(bf16x8, a1u & mm1);
                    acc00 = __builtin_amdgcn_mfma_f32_32x32x16_bf16(a0m, b0, acc00, 0, 0, 0);
                    acc01 = __builtin_amdgcn_mfma_f32_32x32x16_bf16(a0m, b1, acc01, 0, 0, 0);
                    acc10 = __builtin_amdgcn_mfma_f32_32x32x16_bf16(a1m, b0, acc10, 0, 0, 0);
                    acc11 = __builtin_amdgcn_mfma_f32_32x32x16_bf16(a1m, b1, acc11, 0, 0, 0);
                }
            }
        }
    }

    // ---- epilogue: C/D layout col=lane&31, row=(reg&3)+8*(reg>>2)+4*(lane>>5)
    // rows scattered through rowid[] (LDS, written pre-barrier); within a row,
    // half-wave writes 128B contiguous segments.
    const int colb = kout * 128 + nhalf * 64 + m0;
    const int rh = (lane >> 5) << 2;
#pragma unroll
    for (int q = 0; q < 4; q++) {
#pragma unroll
        for (int d = 0; d < 4; d++) {
            int reg = q * 4 + d;
            int rl = d + 8 * q + rh;
            float* o0 = out + (size_t)rowid[rl] * OUT_STRIDE + colb;
            float* o1 = out + (size_t)rowid[rl + 32] * OUT_STRIDE + colb;
            o0[0]  = acc00[reg];
            o0[32] = acc01[reg];
            o1[0]  = acc10[reg];
            o1[32] = acc11[reg];
        }
    }
}

extern "C" void kernel_launch(void* const* d_in, const int* in_sizes, int n_in,
                              void* d_out, int out_size, void* d_ws, size_t ws_size,
                              hipStream_t stream) {
    const float* x = (const float*)d_in[0];
    const float* w = (const float*)d_in[1];
    const int* wid = (const int*)d_in[2];
    float* out = (float*)d_out;

    unsigned short* wshuf = (unsigned short*)((char*)d_ws + WS_WSHUF);
    unsigned int* cnt = (unsigned int*)((char*)d_ws + WS_CNT);
    int* sorted = (int*)((char*)d_ws + WS_SORT);

    prep_kernel<<<256, 256, 0, stream>>>(w, wshuf, cnt);
    scatter_kernel<<<128, 256, 0, stream>>>(wid, cnt, sorted);
    gemm_kernel<<<512, 512, 0, stream>>>(x, wshuf, cnt, sorted, out);
}